// Round 6
// baseline (279.671 us; speedup 1.0000x reference)
//
#include <hip/hip_runtime.h>
#include <hip/hip_bf16.h>

// CoordinateDescent: B=8, M=N=2048, R=32, f32 in/out.
// l1 = l2 = 0.01*0.5*2048 = 10.24 for both factors.
//
// 4 dispatches, KSPLIT=8 split-K partials, depth-2 x prefetch (4 dwordx4 in
// flight per lane), pre-barrier initial x loads, nontemporal ap traffic:
//   fused1 = bmat(v) partials + gemm1 split-K partials   (256+2048 blocks)
//   gs     = reduce partials + Gauss-Seidel -> out_u     (256 blocks)
//   fused2 = bmat(out_u) partials + gemm2 split-K partials
//   gs     = reduce partials + Gauss-Seidel -> out_v
// launch_bounds(256,4): VGPR cap 128 so depth-2 prefetch can't spill; round-1
// vs round-4 A/B proved 16 vs 32 waves/CU is perf-neutral here, so any
// occupancy change from extra VGPRs is free.
// Workspace: ap = [B,2048,KSPLIT,32] f32 (16 MB) + bp = [B,32,32,32] f32 (1 MB).
#define NB 8
#define MD 2048
#define RD 32
#define KSPLIT 8
#define KSL (2048 / KSPLIT)  // 256
#define NSTEP (KSL / 32)     // 8
#define VT_STRIDE 264        // shorts per row of wT (256 + 8 pad), 528B = 16B-aligned
#define XT_STRIDE 40         // shorts per row of xT (32 + 8 pad), 80B = 16B-aligned
#define GEMM_BLOCKS (NB * 32 * KSPLIT)  // 2048

typedef float floatx4 __attribute__((ext_vector_type(4)));
typedef short shortx8 __attribute__((ext_vector_type(8)));

static __device__ __forceinline__ short f2b(float f) {
    __hip_bfloat16 h = __float2bfloat16(f);
    return (short)*reinterpret_cast<unsigned short*>(&h);
}

// -------- bmat partial: bp[b,slice,i,j] = sum over 64 rows of w[b,n,i]*w[b,n,j] ------
static __device__ __forceinline__ void bmat_part(const float* __restrict__ w,
                                                 float* __restrict__ bp,
                                                 int bz, int t, char* smem) {
    int batch = bz >> 5;
    int slice = bz & 31;
    float* ws = (float*)smem;  // [64][36]; row stride 144B keeps float4 reads aligned
    const float* wb = w + ((size_t)batch * 2048 + slice * 64) * RD;
#pragma unroll
    for (int i = 0; i < 8; ++i) {
        int idx = t + i * 256;
        ws[(idx >> 5) * 36 + (idx & 31)] = wb[(idx >> 5) * RD + (idx & 31)];
    }
    __syncthreads();
    int ii = t >> 3;
    int jq = (t & 7) * 4;
    float a0 = 0.f, a1 = 0.f, a2 = 0.f, a3 = 0.f;
    for (int n = 0; n < 64; ++n) {
        float wi = ws[n * 36 + ii];
        float4 wj = *(const float4*)&ws[n * 36 + jq];
        a0 = fmaf(wi, wj.x, a0);
        a1 = fmaf(wi, wj.y, a1);
        a2 = fmaf(wi, wj.z, a2);
        a3 = fmaf(wi, wj.w, a3);
    }
    float4 r = {a0, a1, a2, a3};
    *(float4*)(bp + (((size_t)batch * 32 + slice) * RD + ii) * RD + jq) = r;
}

// -------- fused1: bmat(v) + GEMM1 ap[b,m,ks,r] = sum_k x[b,m,k]*v[b,k,r] ----------
__global__ __launch_bounds__(256, 4) void fused1_kernel(const float* __restrict__ x,
                                                        const float* __restrict__ v,
                                                        float* __restrict__ ap,
                                                        float* __restrict__ bp) {
    __shared__ __align__(16) char smem[32 * VT_STRIDE * 2];  // 16896 B
    int bz = blockIdx.x;
    int t = threadIdx.x;
    if (bz < NB * 32) {
        bmat_part(v, bp, bz, t, smem);
        return;
    }
    bz -= NB * 32;
    short* wT = (short*)smem;  // vT[r][k] bf16, k slice-local
    int ks = bz & (KSPLIT - 1);
    int mblk = (bz >> 3) & 31;
    int batch = bz >> 8;
    int lane = t & 63;
    int wave = t >> 6;

    // issue the first two x A-tile loads BEFORE staging: latency hides under it
    int kq = (lane >> 4) * 8;
    const float* xrow =
        x + ((size_t)batch * MD + mblk * 64 + wave * 16 + (lane & 15)) * 2048 + ks * KSL + kq;
    float4 A0 = *(const float4*)(xrow);
    float4 B0 = *(const float4*)(xrow + 4);
    float4 A1 = *(const float4*)(xrow + 32);
    float4 B1 = *(const float4*)(xrow + 36);

    // stage vT: v[ks*KSL + k][r] -> wT[r][k], coalesced f32 loads (8 iters)
    const float* wb = v + ((size_t)batch * 2048 + ks * KSL) * RD;
#pragma unroll
    for (int i = 0; i < 8; ++i) {
        int idx = t + i * 256;
        int k = idx >> 3;
        int rq = (idx & 7) * 4;
        float4 f = *(const float4*)(wb + (size_t)k * RD + rq);
        wT[(rq + 0) * VT_STRIDE + k] = f2b(f.x);
        wT[(rq + 1) * VT_STRIDE + k] = f2b(f.y);
        wT[(rq + 2) * VT_STRIDE + k] = f2b(f.z);
        wT[(rq + 3) * VT_STRIDE + k] = f2b(f.w);
    }
    __syncthreads();

    int r0 = (lane & 15) * VT_STRIDE + kq;
    int r1 = ((lane & 15) + 16) * VT_STRIDE + kq;

    floatx4 acc0 = {0.f, 0.f, 0.f, 0.f}, acc1 = {0.f, 0.f, 0.f, 0.f};
    for (int s = 0; s < NSTEP; ++s) {
        float4 A2 = {0, 0, 0, 0}, B2 = {0, 0, 0, 0};
        if (s + 2 < NSTEP) {  // depth-2 register prefetch
            A2 = *(const float4*)(xrow + (s + 2) * 32);
            B2 = *(const float4*)(xrow + (s + 2) * 32 + 4);
        }
        shortx8 af = {f2b(A0.x), f2b(A0.y), f2b(A0.z), f2b(A0.w),
                      f2b(B0.x), f2b(B0.y), f2b(B0.z), f2b(B0.w)};
        shortx8 b0 = *(const shortx8*)&wT[r0 + s * 32];
        shortx8 b1 = *(const shortx8*)&wT[r1 + s * 32];
        acc0 = __builtin_amdgcn_mfma_f32_16x16x32_bf16(af, b0, acc0, 0, 0, 0);
        acc1 = __builtin_amdgcn_mfma_f32_16x16x32_bf16(af, b1, acc1, 0, 0, 0);
        A0 = A1; B0 = B1; A1 = A2; B1 = B2;
    }
    // D: col = lane&15, row = (lane>>4)*4 + i; layout [b, m, ks, r]; nt stores
    float* ab = ap +
                (((size_t)batch * 2048 + mblk * 64 + wave * 16 + (lane >> 4) * 4) * KSPLIT + ks) * RD +
                (lane & 15);
#pragma unroll
    for (int i = 0; i < 4; ++i) {
        __builtin_nontemporal_store(acc0[i], ab + i * KSPLIT * RD);
        __builtin_nontemporal_store(acc1[i], ab + i * KSPLIT * RD + 16);
    }
}

// -------- fused2: bmat(u) + GEMM2 ap[b,n,ks,r] = sum_m x[b,m,n]*u[b,m,r] ----------
// Per-step wave-private LDS transpose of the 32x16 x-tile; no per-step barriers.
__global__ __launch_bounds__(256, 4) void fused2_kernel(const float* __restrict__ x,
                                                        const float* __restrict__ u,
                                                        float* __restrict__ ap,
                                                        float* __restrict__ bp) {
    __shared__ __align__(16) short smem[32 * VT_STRIDE + 4 * 16 * XT_STRIDE];  // 22016 B
    int bz = blockIdx.x;
    int t = threadIdx.x;
    if (bz < NB * 32) {
        bmat_part(u, bp, bz, t, (char*)smem);
        return;
    }
    bz -= NB * 32;
    short* uT = smem;                        // uT[r][m] bf16
    short* xT = smem + 32 * VT_STRIDE;       // per-wave 16n x 32m bf16
    int ks = bz & (KSPLIT - 1);
    int nblk = (bz >> 3) & 31;
    int batch = bz >> 8;
    int lane = t & 63;
    int wave = t >> 6;

    // issue the first two x tile loads BEFORE staging
    int mloc = lane & 31;            // row of the 32-row k-step tile this lane loads
    int ng = (lane >> 5) * 8;        // wave-local col group (0 or 8)
    int n0w = nblk * 64 + wave * 16;
    const float* xp = x + ((size_t)batch * 2048 + ks * KSL + mloc) * 2048 + n0w + ng;
    float4 A0 = *(const float4*)xp;
    float4 B0 = *(const float4*)(xp + 4);
    float4 A1 = *(const float4*)(xp + (size_t)32 * 2048);
    float4 B1 = *(const float4*)(xp + (size_t)32 * 2048 + 4);

    const float* ub = u + ((size_t)batch * 2048 + ks * KSL) * RD;
#pragma unroll
    for (int i = 0; i < 8; ++i) {
        int idx = t + i * 256;
        int k = idx >> 3;
        int rq = (idx & 7) * 4;
        float4 f = *(const float4*)(ub + (size_t)k * RD + rq);
        uT[(rq + 0) * VT_STRIDE + k] = f2b(f.x);
        uT[(rq + 1) * VT_STRIDE + k] = f2b(f.y);
        uT[(rq + 2) * VT_STRIDE + k] = f2b(f.z);
        uT[(rq + 3) * VT_STRIDE + k] = f2b(f.w);
    }
    __syncthreads();

    short* xTw = &xT[wave * 16 * XT_STRIDE];
    int nl = lane & 15;
    int kq = (lane >> 4) * 8;
    int rA = nl * XT_STRIDE + kq;
    int rB0 = nl * VT_STRIDE + kq;
    int rB1 = (nl + 16) * VT_STRIDE + kq;

    floatx4 acc0 = {0.f, 0.f, 0.f, 0.f}, acc1 = {0.f, 0.f, 0.f, 0.f};
    for (int s = 0; s < NSTEP; ++s) {
        // transpose-store this step's x tile (wave-private; in-order DS = safe)
        xTw[(ng + 0) * XT_STRIDE + mloc] = f2b(A0.x);
        xTw[(ng + 1) * XT_STRIDE + mloc] = f2b(A0.y);
        xTw[(ng + 2) * XT_STRIDE + mloc] = f2b(A0.z);
        xTw[(ng + 3) * XT_STRIDE + mloc] = f2b(A0.w);
        xTw[(ng + 4) * XT_STRIDE + mloc] = f2b(B0.x);
        xTw[(ng + 5) * XT_STRIDE + mloc] = f2b(B0.y);
        xTw[(ng + 6) * XT_STRIDE + mloc] = f2b(B0.z);
        xTw[(ng + 7) * XT_STRIDE + mloc] = f2b(B0.w);
        float4 A2 = {0, 0, 0, 0}, B2 = {0, 0, 0, 0};
        if (s + 2 < NSTEP) {  // depth-2 register prefetch
            A2 = *(const float4*)(xp + (size_t)(s + 2) * 32 * 2048);
            B2 = *(const float4*)(xp + (size_t)(s + 2) * 32 * 2048 + 4);
        }
        shortx8 af = *(const shortx8*)&xTw[rA];
        shortx8 b0 = *(const shortx8*)&uT[rB0 + s * 32];
        shortx8 b1 = *(const shortx8*)&uT[rB1 + s * 32];
        acc0 = __builtin_amdgcn_mfma_f32_16x16x32_bf16(af, b0, acc0, 0, 0, 0);
        acc1 = __builtin_amdgcn_mfma_f32_16x16x32_bf16(af, b1, acc1, 0, 0, 0);
        A0 = A1; B0 = B1; A1 = A2; B1 = B2;
    }
    float* ab = ap +
                (((size_t)batch * 2048 + n0w + (lane >> 4) * 4) * KSPLIT + ks) * RD +
                (lane & 15);
#pragma unroll
    for (int i = 0; i < 4; ++i) {
        __builtin_nontemporal_store(acc0[i], ab + i * KSPLIT * RD);
        __builtin_nontemporal_store(acc1[i], ab + i * KSPLIT * RD + 16);
    }
}

// -------- GS: reduce partials + Gauss-Seidel over r; 256 blocks, 64 rows each -------
__global__ __launch_bounds__(256) void gs_kernel(const float* __restrict__ uin,
                                                 const float* __restrict__ ap,
                                                 const float* __restrict__ bp,
                                                 float* __restrict__ uout,
                                                 float l1, float l2) {
    int bz = blockIdx.x;  // [0, 256): batch = bz>>5, 64-row group = bz&31
    int batch = bz >> 5;
    __shared__ float bs[RD * RD];
    // reduce the 32 bmat partial slices; thread t owns 4 consecutive floats
    {
        const float4* bpp = (const float4*)(bp + (size_t)batch * 32 * RD * RD) + threadIdx.x;
        float4 bacc = {0.f, 0.f, 0.f, 0.f};
#pragma unroll
        for (int s = 0; s < 32; ++s) {
            float4 f = bpp[s * 256];
            bacc.x += f.x;
            bacc.y += f.y;
            bacc.z += f.z;
            bacc.w += f.w;
        }
        ((float4*)bs)[threadIdx.x] = bacc;
    }
    __syncthreads();
    int t = threadIdx.x;
    if (t >= 64) return;  // 64 worker threads, one row each
    int m = (bz & 31) * 64 + t;
    float uv[RD], av[RD];
    const float* up = uin + ((size_t)batch * 2048 + m) * RD;
    const float* app = ap + ((size_t)batch * 2048 + m) * (KSPLIT * RD);  // 1 KB contiguous
#pragma unroll
    for (int q = 0; q < 8; ++q) {
        *(float4*)&uv[q * 4] = *(const float4*)&up[q * 4];
        floatx4 r = {0.f, 0.f, 0.f, 0.f};
#pragma unroll
        for (int s = 0; s < KSPLIT; ++s) {
            // nontemporal: ext_vector_type pointer (HIP float4* is rejected)
            floatx4 f = __builtin_nontemporal_load((const floatx4*)(app + s * RD + q * 4));
            r += f;
        }
        av[q * 4 + 0] = r.x;
        av[q * 4 + 1] = r.y;
        av[q * 4 + 2] = r.z;
        av[q * 4 + 3] = r.w;
    }
#pragma unroll
    for (int r = 0; r < RD; ++r) {
        float brr = bs[r * RD + r];
        // 4 independent FMA chains (dep latency ~44cy/r vs 128cy serial)
        float4 t2v = {0.f, 0.f, 0.f, 0.f};
#pragma unroll
        for (int q = 0; q < 8; ++q) {
            float4 bq = *(const float4*)&bs[r * RD + q * 4];
            t2v.x = fmaf(uv[q * 4 + 0], bq.x, t2v.x);
            t2v.y = fmaf(uv[q * 4 + 1], bq.y, t2v.y);
            t2v.z = fmaf(uv[q * 4 + 2], bq.z, t2v.z);
            t2v.w = fmaf(uv[q * 4 + 3], bq.w, t2v.w);
        }
        float t2 = ((t2v.x + t2v.y) + (t2v.z + t2v.w)) - uv[r] * brr;
        float num = av[r] - t2;
        float mag = fmaxf(fabsf(num) - l1, 0.f);
        num = copysignf(mag, num);
        uv[r] = (num + 1e-16f) / (brr + l2 + 1e-16f);
    }
    float* op = uout + ((size_t)batch * 2048 + m) * RD;
#pragma unroll
    for (int q = 0; q < 8; ++q) *(float4*)&op[q * 4] = *(float4*)&uv[q * 4];
}

extern "C" void kernel_launch(void* const* d_in, const int* in_sizes, int n_in,
                              void* d_out, int out_size, void* d_ws, size_t ws_size,
                              hipStream_t stream) {
    const float* x = (const float*)d_in[0];
    const float* u = (const float*)d_in[1];
    const float* v = (const float*)d_in[2];
    float* out_u = (float*)d_out;
    float* out_v = out_u + (size_t)NB * MD * RD;
    float* ap = (float*)d_ws;                              // [B,2048,8,32] f32 = 16 MB
    float* bp = ap + (size_t)NB * 2048 * KSPLIT * RD;      // [B,32,32,32] f32 = 1 MB
    const float l1u = 10.24f, l2u = 10.24f;
    const float l1v = 10.24f, l2v = 10.24f;
    const int GRID = NB * 32 + GEMM_BLOCKS;  // 256 bmat + 2048 gemm blocks

    // ---- factor 0: update u ----
    fused1_kernel<<<GRID, 256, 0, stream>>>(x, v, ap, bp);
    gs_kernel<<<NB * 32, 256, 0, stream>>>(u, ap, bp, out_u, l1u, l2u);

    // ---- factor 1: update v ----
    fused2_kernel<<<GRID, 256, 0, stream>>>(x, out_u, ap, bp);
    gs_kernel<<<NB * 32, 256, 0, stream>>>(v, ap, bp, out_v, l1v, l2v);
}

// Round 7
// 252.981 us; speedup vs baseline: 1.1055x; 1.1055x over previous
//
#include <hip/hip_runtime.h>
#include <hip/hip_bf16.h>

// CoordinateDescent: B=8, M=N=2048, R=32, f32 in/out.
// l1 = l2 = 0.01*0.5*2048 = 10.24 for both factors.
//
// Best-measured configuration (254.4 us): 4 dispatches, no memsets, no atomics.
//   fused1 = bmat(v) partials + gemm1 split-K partials   (1280 blocks)
//   gs     = reduce partials + Gauss-Seidel -> out_u
//   fused2 = bmat(out_u) partials + gemm2 split-K partials
//   gs     = reduce partials + Gauss-Seidel -> out_v
// Ledger (rounds 0-6): occupancy x2 (KSPLIT=8) +2.9us; depth-2 prefetch +
// nontemporal +22us; spin-barrier mega +806us; atomics/memset removal -0.8us.
// Conclusion: controllable region is near its BW floor; measured dur is
// dominated by ~155us of fixed harness fill (512MiB @ 86% peak x2-3 in region).
// Workspace: ap = 4 x [B,2048,32] f32 (8 MB) + bp = [B,32,32,32] f32 (1 MB).
#define NB 8
#define MD 2048
#define RD 32
#define KSPLIT 4
#define KSL (2048 / KSPLIT)  // 512
#define VT_STRIDE 520        // shorts per row of wT (512 + 8 pad), 1040B = 16B-aligned
#define XT_STRIDE 40         // shorts per row of xT (32 + 8 pad), 80B = 16B-aligned
#define ASL ((size_t)NB * 2048 * RD)  // floats per a-partial slice (524288)

typedef float floatx4 __attribute__((ext_vector_type(4)));
typedef short shortx8 __attribute__((ext_vector_type(8)));

static __device__ __forceinline__ short f2b(float f) {
    __hip_bfloat16 h = __float2bfloat16(f);
    return (short)*reinterpret_cast<unsigned short*>(&h);
}

// -------- bmat partial: bp[b,slice,i,j] = sum over 64 rows of w[b,n,i]*w[b,n,j] ------
// One 64-row slice per block (bz in [0, NB*32)), plain float4 stores, no atomics.
static __device__ __forceinline__ void bmat_part(const float* __restrict__ w,
                                                 float* __restrict__ bp,
                                                 int bz, int t, char* smem) {
    int batch = bz >> 5;
    int slice = bz & 31;
    float* ws = (float*)smem;  // [64][36]; row stride 144B keeps float4 reads aligned
    const float* wb = w + ((size_t)batch * 2048 + slice * 64) * RD;
#pragma unroll
    for (int i = 0; i < 8; ++i) {
        int idx = t + i * 256;
        ws[(idx >> 5) * 36 + (idx & 31)] = wb[(idx >> 5) * RD + (idx & 31)];
    }
    __syncthreads();
    int ii = t >> 3;
    int jq = (t & 7) * 4;
    float a0 = 0.f, a1 = 0.f, a2 = 0.f, a3 = 0.f;
    for (int n = 0; n < 64; ++n) {
        float wi = ws[n * 36 + ii];
        float4 wj = *(const float4*)&ws[n * 36 + jq];
        a0 = fmaf(wi, wj.x, a0);
        a1 = fmaf(wi, wj.y, a1);
        a2 = fmaf(wi, wj.z, a2);
        a3 = fmaf(wi, wj.w, a3);
    }
    float4 r = {a0, a1, a2, a3};
    *(float4*)(bp + (((size_t)batch * 32 + slice) * RD + ii) * RD + jq) = r;
}

// -------- fused1: bmat(v) + GEMM1 ap[ks][b,m,r] = sum_k x[b,m,k]*v[b,k,r] ----------
__global__ __launch_bounds__(256, 4) void fused1_kernel(const float* __restrict__ x,
                                                        const float* __restrict__ v,
                                                        float* __restrict__ ap,
                                                        float* __restrict__ bp) {
    __shared__ __align__(16) char smem[32 * VT_STRIDE * 2];  // 33.3 KB (bmat uses 9.2 KB)
    int bz = blockIdx.x;
    int t = threadIdx.x;
    if (bz < NB * 32) {
        bmat_part(v, bp, bz, t, smem);
        return;
    }
    bz -= NB * 32;
    short* wT = (short*)smem;  // vT[r][k] bf16, k slice-local
    int ks = bz & (KSPLIT - 1);
    int mblk = (bz >> 2) & 31;
    int batch = bz >> 7;
    int lane = t & 63;
    int wave = t >> 6;

    // stage vT: v[ks*KSL + k][r] -> wT[r][k], coalesced f32 loads
    const float* wb = v + ((size_t)batch * 2048 + ks * KSL) * RD;
#pragma unroll
    for (int i = 0; i < 16; ++i) {
        int idx = t + i * 256;
        int k = idx >> 3;
        int rq = (idx & 7) * 4;
        float4 f = *(const float4*)(wb + (size_t)k * RD + rq);
        wT[(rq + 0) * VT_STRIDE + k] = f2b(f.x);
        wT[(rq + 1) * VT_STRIDE + k] = f2b(f.y);
        wT[(rq + 2) * VT_STRIDE + k] = f2b(f.z);
        wT[(rq + 3) * VT_STRIDE + k] = f2b(f.w);
    }
    __syncthreads();

    // A-frag: A[m=lane&15][k=(lane>>4)*8+j], direct from global x (f32 -> bf16)
    int kq = (lane >> 4) * 8;
    const float* xrow =
        x + ((size_t)batch * MD + mblk * 64 + wave * 16 + (lane & 15)) * 2048 + ks * KSL + kq;
    int r0 = (lane & 15) * VT_STRIDE + kq;
    int r1 = ((lane & 15) + 16) * VT_STRIDE + kq;

    floatx4 acc0 = {0.f, 0.f, 0.f, 0.f}, acc1 = {0.f, 0.f, 0.f, 0.f};
    float4 fa = *(const float4*)(xrow);
    float4 fb = *(const float4*)(xrow + 4);
    for (int s = 0; s < KSL / 32; ++s) {
        float4 na = {0, 0, 0, 0}, nb = {0, 0, 0, 0};
        if (s + 1 < KSL / 32) {  // register prefetch of next A-tile
            na = *(const float4*)(xrow + (s + 1) * 32);
            nb = *(const float4*)(xrow + (s + 1) * 32 + 4);
        }
        shortx8 af = {f2b(fa.x), f2b(fa.y), f2b(fa.z), f2b(fa.w),
                      f2b(fb.x), f2b(fb.y), f2b(fb.z), f2b(fb.w)};
        shortx8 b0 = *(const shortx8*)&wT[r0 + s * 32];
        shortx8 b1 = *(const shortx8*)&wT[r1 + s * 32];
        acc0 = __builtin_amdgcn_mfma_f32_16x16x32_bf16(af, b0, acc0, 0, 0, 0);
        acc1 = __builtin_amdgcn_mfma_f32_16x16x32_bf16(af, b1, acc1, 0, 0, 0);
        fa = na;
        fb = nb;
    }
    // D: col = lane&15, row = (lane>>4)*4 + i; plain stores into this ks slice
    float* ab = ap + ks * ASL +
                ((size_t)batch * 2048 + mblk * 64 + wave * 16 + (lane >> 4) * 4) * RD +
                (lane & 15);
#pragma unroll
    for (int i = 0; i < 4; ++i) {
        ab[i * RD] = acc0[i];
        ab[i * RD + 16] = acc1[i];
    }
}

// -------- fused2: bmat(u) + GEMM2 ap[ks][b,n,r] = sum_m x[b,m,n]*u[b,m,r] ----------
// Per-step wave-private LDS transpose of the 32x16 x-tile; no per-step barriers.
__global__ __launch_bounds__(256, 4) void fused2_kernel(const float* __restrict__ x,
                                                        const float* __restrict__ u,
                                                        float* __restrict__ ap,
                                                        float* __restrict__ bp) {
    __shared__ __align__(16) short smem[32 * VT_STRIDE + 4 * 16 * XT_STRIDE];  // 38.4 KB
    int bz = blockIdx.x;
    int t = threadIdx.x;
    if (bz < NB * 32) {
        bmat_part(u, bp, bz, t, (char*)smem);
        return;
    }
    bz -= NB * 32;
    short* uT = smem;                        // uT[r][m] bf16
    short* xT = smem + 32 * VT_STRIDE;       // per-wave 16n x 32m bf16
    int ks = bz & (KSPLIT - 1);
    int nblk = (bz >> 2) & 31;
    int batch = bz >> 7;
    int lane = t & 63;
    int wave = t >> 6;

    const float* ub = u + ((size_t)batch * 2048 + ks * KSL) * RD;
#pragma unroll
    for (int i = 0; i < 16; ++i) {
        int idx = t + i * 256;
        int k = idx >> 3;
        int rq = (idx & 7) * 4;
        float4 f = *(const float4*)(ub + (size_t)k * RD + rq);
        uT[(rq + 0) * VT_STRIDE + k] = f2b(f.x);
        uT[(rq + 1) * VT_STRIDE + k] = f2b(f.y);
        uT[(rq + 2) * VT_STRIDE + k] = f2b(f.z);
        uT[(rq + 3) * VT_STRIDE + k] = f2b(f.w);
    }
    __syncthreads();

    short* xTw = &xT[wave * 16 * XT_STRIDE];
    int mloc = lane & 31;            // row of the 32-row k-step tile this lane loads
    int ng = (lane >> 5) * 8;        // wave-local col group (0 or 8)
    int n0w = nblk * 64 + wave * 16;
    const float* xp = x + ((size_t)batch * 2048 + ks * KSL + mloc) * 2048 + n0w + ng;

    int nl = lane & 15;
    int kq = (lane >> 4) * 8;
    int rA = nl * XT_STRIDE + kq;
    int rB0 = nl * VT_STRIDE + kq;
    int rB1 = (nl + 16) * VT_STRIDE + kq;

    floatx4 acc0 = {0.f, 0.f, 0.f, 0.f}, acc1 = {0.f, 0.f, 0.f, 0.f};
    float4 fa = *(const float4*)xp;
    float4 fb = *(const float4*)(xp + 4);
    for (int s = 0; s < KSL / 32; ++s) {
        // transpose-store this step's x tile (wave-private; in-order DS = safe)
        xTw[(ng + 0) * XT_STRIDE + mloc] = f2b(fa.x);
        xTw[(ng + 1) * XT_STRIDE + mloc] = f2b(fa.y);
        xTw[(ng + 2) * XT_STRIDE + mloc] = f2b(fa.z);
        xTw[(ng + 3) * XT_STRIDE + mloc] = f2b(fa.w);
        xTw[(ng + 4) * XT_STRIDE + mloc] = f2b(fb.x);
        xTw[(ng + 5) * XT_STRIDE + mloc] = f2b(fb.y);
        xTw[(ng + 6) * XT_STRIDE + mloc] = f2b(fb.z);
        xTw[(ng + 7) * XT_STRIDE + mloc] = f2b(fb.w);
        float4 na = {0, 0, 0, 0}, nb = {0, 0, 0, 0};
        if (s + 1 < KSL / 32) {  // prefetch next 32 rows
            na = *(const float4*)(xp + (size_t)(s + 1) * 32 * 2048);
            nb = *(const float4*)(xp + (size_t)(s + 1) * 32 * 2048 + 4);
        }
        shortx8 af = *(const shortx8*)&xTw[rA];
        shortx8 b0 = *(const shortx8*)&uT[rB0 + s * 32];
        shortx8 b1 = *(const shortx8*)&uT[rB1 + s * 32];
        acc0 = __builtin_amdgcn_mfma_f32_16x16x32_bf16(af, b0, acc0, 0, 0, 0);
        acc1 = __builtin_amdgcn_mfma_f32_16x16x32_bf16(af, b1, acc1, 0, 0, 0);
        fa = na;
        fb = nb;
    }
    float* ab = ap + ks * ASL +
                ((size_t)batch * 2048 + n0w + (lane >> 4) * 4) * RD + (lane & 15);
#pragma unroll
    for (int i = 0; i < 4; ++i) {
        ab[i * RD] = acc0[i];
        ab[i * RD + 16] = acc1[i];
    }
}

// -------- GS: reduce partials + Gauss-Seidel over r, parallel over (batch,row) ------
__global__ __launch_bounds__(256) void gs_kernel(const float* __restrict__ uin,
                                                 const float* __restrict__ ap,
                                                 const float* __restrict__ bp,
                                                 float* __restrict__ uout,
                                                 float l1, float l2) {
    int blk = blockIdx.x;
    int batch = blk >> 3;
    int m = (blk & 7) * 256 + threadIdx.x;
    __shared__ float bs[RD][RD];
    // reduce the 32 bmat partial slices; thread t owns 4 consecutive floats
    {
        const float4* bpp = (const float4*)(bp + (size_t)batch * 32 * RD * RD) + threadIdx.x;
        float4 bacc = {0.f, 0.f, 0.f, 0.f};
#pragma unroll
        for (int s = 0; s < 32; ++s) {
            float4 f = bpp[s * 256];
            bacc.x += f.x;
            bacc.y += f.y;
            bacc.z += f.z;
            bacc.w += f.w;
        }
        ((float4*)&bs[0][0])[threadIdx.x] = bacc;
    }
    __syncthreads();
    float uv[RD], av[RD];
    const float* up = uin + ((size_t)batch * 2048 + m) * RD;
    const float* app = ap + ((size_t)batch * 2048 + m) * RD;
#pragma unroll
    for (int q = 0; q < 8; ++q) {
        *(float4*)&uv[q * 4] = *(const float4*)&up[q * 4];
        float4 s0 = *(const float4*)(app + q * 4);
        float4 s1 = *(const float4*)(app + ASL + q * 4);
        float4 s2 = *(const float4*)(app + 2 * ASL + q * 4);
        float4 s3 = *(const float4*)(app + 3 * ASL + q * 4);
        float4 r;
        r.x = (s0.x + s1.x) + (s2.x + s3.x);
        r.y = (s0.y + s1.y) + (s2.y + s3.y);
        r.z = (s0.z + s1.z) + (s2.z + s3.z);
        r.w = (s0.w + s1.w) + (s2.w + s3.w);
        *(float4*)&av[q * 4] = r;
    }
#pragma unroll
    for (int r = 0; r < RD; ++r) {
        float brr = bs[r][r];
        // 4 independent FMA chains (dep latency ~44cy/r vs 128cy serial)
        float4 t2v = {0.f, 0.f, 0.f, 0.f};
#pragma unroll
        for (int q = 0; q < 8; ++q) {
            float4 bq = *(const float4*)&bs[r][q * 4];
            t2v.x = fmaf(uv[q * 4 + 0], bq.x, t2v.x);
            t2v.y = fmaf(uv[q * 4 + 1], bq.y, t2v.y);
            t2v.z = fmaf(uv[q * 4 + 2], bq.z, t2v.z);
            t2v.w = fmaf(uv[q * 4 + 3], bq.w, t2v.w);
        }
        float t2 = ((t2v.x + t2v.y) + (t2v.z + t2v.w)) - uv[r] * brr;
        float num = av[r] - t2;
        float mag = fmaxf(fabsf(num) - l1, 0.f);
        num = copysignf(mag, num);
        uv[r] = (num + 1e-16f) / (brr + l2 + 1e-16f);
    }
    float* op = uout + ((size_t)batch * 2048 + m) * RD;
#pragma unroll
    for (int q = 0; q < 8; ++q) *(float4*)&op[q * 4] = *(float4*)&uv[q * 4];
}

extern "C" void kernel_launch(void* const* d_in, const int* in_sizes, int n_in,
                              void* d_out, int out_size, void* d_ws, size_t ws_size,
                              hipStream_t stream) {
    const float* x = (const float*)d_in[0];
    const float* u = (const float*)d_in[1];
    const float* v = (const float*)d_in[2];
    float* out_u = (float*)d_out;
    float* out_v = out_u + (size_t)NB * MD * RD;
    float* ap = (float*)d_ws;                 // 4 x [B,2048,32] f32 = 8 MB
    float* bp = ap + KSPLIT * ASL;            // [B,32,32,32] f32 = 1 MB
    const float l1u = 10.24f, l2u = 10.24f;
    const float l1v = 10.24f, l2v = 10.24f;
    const int GRID = NB * 32 + NB * 32 * KSPLIT;  // 256 bmat + 1024 gemm blocks

    // ---- factor 0: update u ----
    fused1_kernel<<<GRID, 256, 0, stream>>>(x, v, ap, bp);
    gs_kernel<<<NB * 8, 256, 0, stream>>>(u, ap, bp, out_u, l1u, l2u);

    // ---- factor 1: update v ----
    fused2_kernel<<<GRID, 256, 0, stream>>>(x, out_u, ap, bp);
    gs_kernel<<<NB * 8, 256, 0, stream>>>(v, ap, bp, out_v, l1v, l2v);
}